// Round 12
// baseline (584.650 us; speedup 1.0000x reference)
//
#include <hip/hip_runtime.h>
#include <hip/hip_cooperative_groups.h>

namespace cg = cooperative_groups;

#define H 64
#define CAP 48      // padded CSR row capacity. deg ~ Poisson(12): P(>48) < 1e-9.

typedef int nint4 __attribute__((ext_vector_type(4)));

// constant-block offsets (floats) — global cst buffer
#define OFF_M   0     // M[i][j] 16x16 : i*16+j
#define OFF_U   256   // u[16]
#define OFF_W   272   // w[16]
#define OFF_C   288   // scalar
#define OFF_R   292   // R[j][i] 4x16 : j*16+i
#define OFF_R0  356   // r0[4]
#define OFF_PV  360   // Pv[i][j] 16x8 : i*8+j
#define OFF_PE  488   // Pe[m][j] 4x8
#define OFF_PS  520   // Ps[i][j] 16x8
#define OFF_BH1 648   // bh1[8]  (bfv @ W1)
#define OFF_BH2 656   // bh2[8]  (bfs @ W1 + b1)
#define CST_N   664

// f32 -> bf16 (RNE), returned in low 16 bits
__device__ __forceinline__ unsigned f2bf(float f) {
    unsigned u = __float_as_uint(f);
    u += 0x7fffu + ((u >> 16) & 1u);
    return u >> 16;
}
__device__ __forceinline__ float bf_lo(unsigned u) { return __uint_as_float(u << 16); }
__device__ __forceinline__ float bf_hi(unsigned u) { return __uint_as_float(u & 0xffff0000u); }

struct Params {
    const int* src; const int* dst; const float4* ea4; const float* x;
    const float* Wx; const float* bx;
    const float* Wq; const float* bq;
    const float* Wk; const float* bk;
    const float* Wv; const float* bv;
    const float* We; const float* Ws; const float* bs;
    const float* W1; const float* b1; const float* W2; const float* b2;
    int* cursor; nint4* csr; float* cst; float* out;
    int N, E;
};

// ---------------------------------------------------------------------------
// fold: collapse all weights to 16-dim operators (r8 derivation):
//   M = Wfq Wfk^T; u = Wfk bfq; w = Wfq bfk; c = bfq.bfk
//   R = We Wfq^T; r0 = We bfq
//   Pv = Wfv W1; Ps = Wfs W1; Pe = We W1; bh1 = bfv W1; bh2 = bfs W1 + b1
// ---------------------------------------------------------------------------
__device__ void do_fold(const Params& P, float* __restrict__ cst)
{
    __shared__ float sWf[4][16][64];
    __shared__ float sbf[4][64];
    const int t = threadIdx.x;
    const int c = t & 63, m = t >> 6;
    const float* W; const float* b;
    switch (m) {
        case 0:  W = P.Wq; b = P.bq; break;
        case 1:  W = P.Wk; b = P.bk; break;
        case 2:  W = P.Wv; b = P.bv; break;
        default: W = P.Ws; b = P.bs; break;
    }
    float acc[16];
#pragma unroll
    for (int i = 0; i < 16; ++i) acc[i] = 0.f;
    float bacc = b[c];
    for (int j = 0; j < 64; ++j) {
        const float wv = W[j * 64 + c];
        bacc += P.bx[j] * wv;
#pragma unroll
        for (int i = 0; i < 16; ++i) acc[i] += P.Wx[i * 64 + j] * wv;
    }
#pragma unroll
    for (int i = 0; i < 16; ++i) sWf[m][i][c] = acc[i];
    sbf[m][c] = bacc;
    __syncthreads();

    {
        const int i = t >> 4, j = t & 15;
        float s = 0.f;
        for (int cc = 0; cc < 64; ++cc) s += sWf[0][i][cc] * sWf[1][j][cc];
        cst[OFF_M + i * 16 + j] = s;
    }
    if (t < 16) {
        float su = 0.f, sw = 0.f;
        for (int cc = 0; cc < 64; ++cc) {
            su += sWf[1][t][cc] * sbf[0][cc];
            sw += sWf[0][t][cc] * sbf[1][cc];
        }
        cst[OFF_U + t] = su;
        cst[OFF_W + t] = sw;
    }
    if (t == 0) {
        float s = 0.f;
        for (int cc = 0; cc < 64; ++cc) s += sbf[0][cc] * sbf[1][cc];
        cst[OFF_C] = s;
    }
    if (t < 64) {
        const int j = t >> 4, i = t & 15;
        float s = 0.f;
        for (int cc = 0; cc < 64; ++cc) s += P.We[j * 64 + cc] * sWf[0][i][cc];
        cst[OFF_R + j * 16 + i] = s;
    }
    if (t < 4) {
        float s = 0.f;
        for (int cc = 0; cc < 64; ++cc) s += P.We[t * 64 + cc] * sbf[0][cc];
        cst[OFF_R0 + t] = s;
    }
    if (t < 128) {
        const int i = t >> 3, j = t & 7;
        float sv = 0.f, ss = 0.f;
        for (int cc = 0; cc < 64; ++cc) {
            const float w1 = P.W1[cc * 8 + j];
            sv += sWf[2][i][cc] * w1;
            ss += sWf[3][i][cc] * w1;
        }
        cst[OFF_PV + i * 8 + j] = sv;
        cst[OFF_PS + i * 8 + j] = ss;
    }
    if (t < 32) {
        const int mm = t >> 3, j = t & 7;
        float s = 0.f;
        for (int cc = 0; cc < 64; ++cc) s += P.We[mm * 64 + cc] * P.W1[cc * 8 + j];
        cst[OFF_PE + mm * 8 + j] = s;
    }
    if (t < 8) {
        float s1 = 0.f, s2 = 0.f;
        for (int cc = 0; cc < 64; ++cc) {
            const float w1 = P.W1[cc * 8 + t];
            s1 += sbf[2][cc] * w1;
            s2 += sbf[3][cc] * w1;
        }
        cst[OFF_BH1 + t] = s1;
        cst[OFF_BH2 + t] = s2 + P.b1[t];
    }
}

// ---------------------------------------------------------------------------
// fill one edge e: bucket record {src, e, bf16x4(A)} into csr[dst*CAP + pos]
// ---------------------------------------------------------------------------
__device__ __forceinline__ void fill_edge(const Params& P, int e)
{
    const int s = P.src[e];
    const int d = P.dst[e];
    const float4 A = P.ea4[e];
    const int pos = atomicAdd(&P.cursor[d], 1);
    if (pos < CAP) {
        nint4 ent;
        ent.x = s;
        ent.y = e;
        ent.z = (int)(f2bf(A.x) | (f2bf(A.y) << 16));
        ent.w = (int)(f2bf(A.z) | (f2bf(A.w) << 16));
        P.csr[(size_t)d * CAP + pos] = ent;
    }
}

// ---------------------------------------------------------------------------
// aggregation for nodes gw, gw+stride, ... — one node per wave, 16 lanes per
// edge-slot (lane cg = x-component), 4 slots/wave, 8 edges in flight.
// alpha = y.x_s + cd + A.r; accumulators T[16] (distributed), S[4], den.
// Epilogue: folded MLP + per-edge output scatter.
// ---------------------------------------------------------------------------
__device__ __forceinline__ void agg_nodes(
    const Params& P, const float* __restrict__ cst, int gw, int stride, int l)
{
    const int grp = l >> 4;
    const int cg_ = l & 15;

    for (int n = gw; n < P.N; n += stride) {
        const int deg = min(P.cursor[n], CAP);
        const size_t nbase = (size_t)n * CAP;

        const float xd = P.x[(size_t)n * 16 + cg_];

        float y = cst[OFF_U + cg_];
#pragma unroll
        for (int i = 0; i < 16; ++i)
            y += __shfl(xd, i) * cst[OFF_M + i * 16 + cg_];

        float pr0 = cst[OFF_R + 0 * 16 + cg_] * xd;
        float pr1 = cst[OFF_R + 1 * 16 + cg_] * xd;
        float pr2 = cst[OFF_R + 2 * 16 + cg_] * xd;
        float pr3 = cst[OFF_R + 3 * 16 + cg_] * xd;
        float pcd = cst[OFF_W + cg_] * xd;
#pragma unroll
        for (int d = 1; d < 16; d <<= 1) {
            pr0 += __shfl_xor(pr0, d);
            pr1 += __shfl_xor(pr1, d);
            pr2 += __shfl_xor(pr2, d);
            pr3 += __shfl_xor(pr3, d);
            pcd += __shfl_xor(pcd, d);
        }
        const float r0 = pr0 + cst[OFF_R0 + 0];
        const float r1 = pr1 + cst[OFF_R0 + 1];
        const float r2 = pr2 + cst[OFF_R0 + 2];
        const float r3 = pr3 + cst[OFF_R0 + 3];
        const float cd = pcd + cst[OFF_C];

        float T = 0.f, S0 = 0.f, S1 = 0.f, S2 = 0.f, S3 = 0.f, den = 0.f;

        for (int base = 0; base < deg; base += 8) {
            const int ia = base + grp;
            const int ib = base + 4 + grp;
            const bool va = ia < deg;
            const bool vb = ib < deg;
            const nint4 Ea = P.csr[nbase + (va ? ia : 0)];
            const nint4 Eb = P.csr[nbase + (vb ? ib : 0)];
            const float xsa = P.x[(size_t)Ea.x * 16 + cg_];
            const float xsb = P.x[(size_t)Eb.x * 16 + cg_];
            {
                const float A0 = bf_lo((unsigned)Ea.z), A1 = bf_hi((unsigned)Ea.z);
                const float A2 = bf_lo((unsigned)Ea.w), A3 = bf_hi((unsigned)Ea.w);
                float p = y * xsa;
                p += __shfl_xor(p, 1);
                p += __shfl_xor(p, 2);
                p += __shfl_xor(p, 4);
                p += __shfl_xor(p, 8);
                p += cd + A0 * r0 + A1 * r1 + A2 * r2 + A3 * r3;
                const float a = va ? __expf(p * 0.125f) : 0.f;
                T += a * xsa;
                S0 += a * A0; S1 += a * A1; S2 += a * A2; S3 += a * A3;
                den += a;
            }
            {
                const float A0 = bf_lo((unsigned)Eb.z), A1 = bf_hi((unsigned)Eb.z);
                const float A2 = bf_lo((unsigned)Eb.w), A3 = bf_hi((unsigned)Eb.w);
                float p = y * xsb;
                p += __shfl_xor(p, 1);
                p += __shfl_xor(p, 2);
                p += __shfl_xor(p, 4);
                p += __shfl_xor(p, 8);
                p += cd + A0 * r0 + A1 * r1 + A2 * r2 + A3 * r3;
                const float a = vb ? __expf(p * 0.125f) : 0.f;
                T += a * xsb;
                S0 += a * A0; S1 += a * A1; S2 += a * A2; S3 += a * A3;
                den += a;
            }
        }

        T   += __shfl_xor(T, 16);   T   += __shfl_xor(T, 32);
        den += __shfl_xor(den, 16); den += __shfl_xor(den, 32);
        S0  += __shfl_xor(S0, 16);  S0  += __shfl_xor(S0, 32);
        S1  += __shfl_xor(S1, 16);  S1  += __shfl_xor(S1, 32);
        S2  += __shfl_xor(S2, 16);  S2  += __shfl_xor(S2, 32);
        S3  += __shfl_xor(S3, 16);  S3  += __shfl_xor(S3, 32);

        const float inv = 1.f / (den + 1e-16f);
        const float Ti = T * inv;

        float hp[8];
#pragma unroll
        for (int j = 0; j < 8; ++j)
            hp[j] = Ti * cst[OFF_PV + cg_ * 8 + j] + xd * cst[OFF_PS + cg_ * 8 + j];
#pragma unroll
        for (int j = 0; j < 8; ++j) {
            hp[j] += __shfl_xor(hp[j], 1);
            hp[j] += __shfl_xor(hp[j], 2);
            hp[j] += __shfl_xor(hp[j], 4);
            hp[j] += __shfl_xor(hp[j], 8);
        }
        const float dinv = den * inv;
        float val = P.b2[0];
#pragma unroll
        for (int j = 0; j < 8; ++j) {
            const float hid = hp[j]
                + inv * (S0 * cst[OFF_PE + 0 * 8 + j] + S1 * cst[OFF_PE + 1 * 8 + j]
                       + S2 * cst[OFF_PE + 2 * 8 + j] + S3 * cst[OFF_PE + 3 * 8 + j])
                + dinv * cst[OFF_BH1 + j] + cst[OFF_BH2 + j];
            val += fmaxf(hid, 0.f) * P.W2[j];
        }

        for (int i = l; i < deg; i += 64)
            P.out[P.csr[nbase + i].y] = val;
    }
}

// ---------------------------------------------------------------------------
// cooperative mega-kernel: zero cursor | gsync | fold (block 0) + fill | gsync
// | aggregation. Grid sized by occupancy query at launch.
// ---------------------------------------------------------------------------
__global__ __launch_bounds__(256) void k_mega(Params P)
{
    const int t = threadIdx.x;
    cg::grid_group grid = cg::this_grid();
    const int gsz = (int)gridDim.x;

    for (int i = blockIdx.x * 256 + t; i < P.N; i += gsz * 256)
        P.cursor[i] = 0;
    grid.sync();

    if (blockIdx.x == 0) {
        do_fold(P, P.cst);
    } else {
        for (int e = (blockIdx.x - 1) * 256 + t; e < P.E; e += (gsz - 1) * 256)
            fill_edge(P, e);
    }
    grid.sync();

    agg_nodes(P, P.cst, blockIdx.x * 4 + (t >> 6), gsz * 4, t & 63);
}

// ---------------------------------------------------------------------------
// fallback path (r8-equivalent, proven 299 us)
// ---------------------------------------------------------------------------
__global__ __launch_bounds__(256) void k_fill_fb(Params P)
{
    if (blockIdx.x == 0) {
        do_fold(P, P.cst);
        return;
    }
    const int e = (blockIdx.x - 1) * 256 + threadIdx.x;
    if (e < P.E) fill_edge(P, e);
}

__global__ __launch_bounds__(256) void k_agg_fb(Params P)
{
    const int t = threadIdx.x;
    const int n = blockIdx.x * 4 + (t >> 6);
    if (n >= P.N) return;
    agg_nodes(P, P.cst, n, 0x40000000, t & 63);
}

// ---------------------------------------------------------------------------
extern "C" void kernel_launch(void* const* d_in, const int* in_sizes, int n_in,
                              void* d_out, int out_size, void* d_ws, size_t ws_size,
                              hipStream_t stream)
{
    Params P;
    P.src = (const int*)d_in[0];
    P.dst = (const int*)d_in[1];
    P.x   = (const float*)d_in[3];
    P.ea4 = (const float4*)d_in[4];
    P.Wx  = (const float*)d_in[5];
    P.bx  = (const float*)d_in[6];
    P.Wq  = (const float*)d_in[7];
    P.bq  = (const float*)d_in[8];
    P.Wk  = (const float*)d_in[9];
    P.bk  = (const float*)d_in[10];
    P.Wv  = (const float*)d_in[11];
    P.bv  = (const float*)d_in[12];
    P.We  = (const float*)d_in[13];
    P.Ws  = (const float*)d_in[14];
    P.bs  = (const float*)d_in[15];
    P.W1  = (const float*)d_in[16];
    P.b1  = (const float*)d_in[17];
    P.W2  = (const float*)d_in[18];
    P.b2  = (const float*)d_in[19];

    P.E = in_sizes[0];
    P.N = in_sizes[3] / 16;
    P.out = (float*)d_out;

    // workspace layout (~77 MB)
    P.csr    = (nint4*)d_ws;                        // N*CAP records
    P.cursor = (int*)(P.csr + (size_t)P.N * CAP);   // N ints
    P.cst    = (float*)(P.cursor + P.N);            // CST_N floats

    // try single cooperative dispatch, sized by occupancy query
    bool done = false;
    int blocksPerCU = 0;
    if (hipOccupancyMaxActiveBlocksPerMultiprocessor(
            &blocksPerCU, (const void*)k_mega, 256, 0) == hipSuccess &&
        blocksPerCU > 0) {
        int grid = blocksPerCU * 256;        // 256 CUs on MI355X
        if (grid > 2048) grid = 2048;
        if (grid >= 64) {
            void* args[] = { &P };
            if (hipLaunchCooperativeKernel((const void*)k_mega, dim3(grid),
                                           dim3(256), args, 0, stream) == hipSuccess)
                done = true;
        }
    }

    if (!done) {
        // fallback: proven 3-dispatch path
        hipMemsetAsync(P.cursor, 0, (size_t)P.N * sizeof(int), stream);
        const int nbE = (P.E + 255) / 256;
        k_fill_fb<<<nbE + 1, 256, 0, stream>>>(P);
        k_agg_fb<<<(P.N + 3) / 4, 256, 0, stream>>>(P);
    }
}

// Round 13
// 291.950 us; speedup vs baseline: 2.0026x; 2.0026x over previous
//
#include <hip/hip_runtime.h>

#define H 64
#define CAP 48      // padded CSR row capacity. deg ~ Poisson(12): P(>48) < 1e-9.

typedef int nint4 __attribute__((ext_vector_type(4)));

// constant-block offsets (floats) — global cst buffer
#define OFF_M   0     // M[i][j] 16x16 : i*16+j
#define OFF_U   256   // u[16]
#define OFF_W   272   // w[16]
#define OFF_C   288   // scalar
#define OFF_R   292   // R[j][i] 4x16 : j*16+i
#define OFF_R0  356   // r0[4]
#define OFF_PV  360   // Pv[i][j] 16x8 : i*8+j
#define OFF_PE  488   // Pe[m][j] 4x8
#define OFF_PS  520   // Ps[i][j] 16x8
#define OFF_BH1 648   // bh1[8]  (bfv @ W1)
#define OFF_BH2 656   // bh2[8]  (bfs @ W1 + b1)
#define CST_N   664

// f32 -> bf16 (RNE), returned in low 16 bits
__device__ __forceinline__ unsigned f2bf(float f) {
    unsigned u = __float_as_uint(f);
    u += 0x7fffu + ((u >> 16) & 1u);
    return u >> 16;
}
__device__ __forceinline__ float bf_lo(unsigned u) { return __uint_as_float(u << 16); }
__device__ __forceinline__ float bf_hi(unsigned u) { return __uint_as_float(u & 0xffff0000u); }

struct Params {
    const int* src; const int* dst; const float4* ea4; const float* x;
    const float* Wx; const float* bx;
    const float* Wq; const float* bq;
    const float* Wk; const float* bk;
    const float* Wv; const float* bv;
    const float* We; const float* Ws; const float* bs;
    const float* W1; const float* b1; const float* W2; const float* b2;
    int* cursor; nint4* csr; float* cst; float* g; float* out;
    int N, E;
};

// ---------------------------------------------------------------------------
// fold (block 0 of k_fill): collapse all weights to 16-dim operators:
//   M = Wfq Wfk^T; u = Wfk bfq; w = Wfq bfk; c = bfq.bfk
//   R = We Wfq^T; r0 = We bfq
//   Pv = Wfv W1; Ps = Wfs W1; Pe = We W1; bh1 = bfv W1; bh2 = bfs W1 + b1
// ---------------------------------------------------------------------------
__device__ void do_fold(const Params& P, float* __restrict__ cst)
{
    __shared__ float sWf[4][16][64];
    __shared__ float sbf[4][64];
    const int t = threadIdx.x;
    const int c = t & 63, m = t >> 6;
    const float* W; const float* b;
    switch (m) {
        case 0:  W = P.Wq; b = P.bq; break;
        case 1:  W = P.Wk; b = P.bk; break;
        case 2:  W = P.Wv; b = P.bv; break;
        default: W = P.Ws; b = P.bs; break;
    }
    float acc[16];
#pragma unroll
    for (int i = 0; i < 16; ++i) acc[i] = 0.f;
    float bacc = b[c];
    for (int j = 0; j < 64; ++j) {
        const float wv = W[j * 64 + c];
        bacc += P.bx[j] * wv;
#pragma unroll
        for (int i = 0; i < 16; ++i) acc[i] += P.Wx[i * 64 + j] * wv;
    }
#pragma unroll
    for (int i = 0; i < 16; ++i) sWf[m][i][c] = acc[i];
    sbf[m][c] = bacc;
    __syncthreads();

    {
        const int i = t >> 4, j = t & 15;
        float s = 0.f;
        for (int cc = 0; cc < 64; ++cc) s += sWf[0][i][cc] * sWf[1][j][cc];
        cst[OFF_M + i * 16 + j] = s;
    }
    if (t < 16) {
        float su = 0.f, sw = 0.f;
        for (int cc = 0; cc < 64; ++cc) {
            su += sWf[1][t][cc] * sbf[0][cc];
            sw += sWf[0][t][cc] * sbf[1][cc];
        }
        cst[OFF_U + t] = su;
        cst[OFF_W + t] = sw;
    }
    if (t == 0) {
        float s = 0.f;
        for (int cc = 0; cc < 64; ++cc) s += sbf[0][cc] * sbf[1][cc];
        cst[OFF_C] = s;
    }
    if (t < 64) {
        const int j = t >> 4, i = t & 15;
        float s = 0.f;
        for (int cc = 0; cc < 64; ++cc) s += P.We[j * 64 + cc] * sWf[0][i][cc];
        cst[OFF_R + j * 16 + i] = s;
    }
    if (t < 4) {
        float s = 0.f;
        for (int cc = 0; cc < 64; ++cc) s += P.We[t * 64 + cc] * sbf[0][cc];
        cst[OFF_R0 + t] = s;
    }
    if (t < 128) {
        const int i = t >> 3, j = t & 7;
        float sv = 0.f, ss = 0.f;
        for (int cc = 0; cc < 64; ++cc) {
            const float w1 = P.W1[cc * 8 + j];
            sv += sWf[2][i][cc] * w1;
            ss += sWf[3][i][cc] * w1;
        }
        cst[OFF_PV + i * 8 + j] = sv;
        cst[OFF_PS + i * 8 + j] = ss;
    }
    if (t < 32) {
        const int mm = t >> 3, j = t & 7;
        float s = 0.f;
        for (int cc = 0; cc < 64; ++cc) s += P.We[mm * 64 + cc] * P.W1[cc * 8 + j];
        cst[OFF_PE + mm * 8 + j] = s;
    }
    if (t < 8) {
        float s1 = 0.f, s2 = 0.f;
        for (int cc = 0; cc < 64; ++cc) {
            const float w1 = P.W1[cc * 8 + t];
            s1 += sbf[2][cc] * w1;
            s2 += sbf[3][cc] * w1;
        }
        cst[OFF_BH1 + t] = s1;
        cst[OFF_BH2 + t] = s2 + P.b1[t];
    }
}

// ---------------------------------------------------------------------------
// K1: block 0 = fold; blocks 1.. bucket edges by dst.
// Record: {src, e, bf16x4(A)} at csr[dst*CAP + pos].
// ---------------------------------------------------------------------------
__global__ __launch_bounds__(256) void k_fill(Params P)
{
    if (blockIdx.x == 0) {
        do_fold(P, P.cst);
        return;
    }
    const int e = (blockIdx.x - 1) * 256 + threadIdx.x;
    if (e >= P.E) return;
    const int s = P.src[e];
    const int d = P.dst[e];
    const float4 A = P.ea4[e];
    const int pos = atomicAdd(&P.cursor[d], 1);
    if (pos < CAP) {
        nint4 ent;
        ent.x = s;
        ent.y = e;
        ent.z = (int)(f2bf(A.x) | (f2bf(A.y) << 16));
        ent.w = (int)(f2bf(A.z) | (f2bf(A.w) << 16));
        P.csr[(size_t)d * CAP + pos] = ent;
    }
}

// ---------------------------------------------------------------------------
// K2: aggregation in 16-dim space. One node per wave, 128-thread blocks
// (2 waves), no LDS, no barrier. 16 lanes per edge-slot, 4 slots/wave,
// 8 edges in flight. alpha = y.x_s + cd + A.r; accumulators T[16]
// (distributed by lane), S[4], den. Epilogue: folded MLP -> g[n] only
// (coalesced; the per-edge scatter lives in k_out to avoid the ~8x
// write-amplification rocprof showed on fused scatter: WRITE 42MB for a
// 4.8MB output).
// ---------------------------------------------------------------------------
__global__ __launch_bounds__(128) void k_agg(Params P)
{
    const int t = threadIdx.x;
    const int l = t & 63;
    const int n = blockIdx.x * 2 + (t >> 6);
    if (n >= P.N) return;
    const int grp = l >> 4;
    const int cg_ = l & 15;
    const float* __restrict__ cst = P.cst;

    const int deg = min(P.cursor[n], CAP);
    const size_t nbase = (size_t)n * CAP;

    const float xd = P.x[(size_t)n * 16 + cg_];

    float y = cst[OFF_U + cg_];
#pragma unroll
    for (int i = 0; i < 16; ++i)
        y += __shfl(xd, i) * cst[OFF_M + i * 16 + cg_];

    float pr0 = cst[OFF_R + 0 * 16 + cg_] * xd;
    float pr1 = cst[OFF_R + 1 * 16 + cg_] * xd;
    float pr2 = cst[OFF_R + 2 * 16 + cg_] * xd;
    float pr3 = cst[OFF_R + 3 * 16 + cg_] * xd;
    float pcd = cst[OFF_W + cg_] * xd;
#pragma unroll
    for (int d = 1; d < 16; d <<= 1) {
        pr0 += __shfl_xor(pr0, d);
        pr1 += __shfl_xor(pr1, d);
        pr2 += __shfl_xor(pr2, d);
        pr3 += __shfl_xor(pr3, d);
        pcd += __shfl_xor(pcd, d);
    }
    const float r0 = pr0 + cst[OFF_R0 + 0];
    const float r1 = pr1 + cst[OFF_R0 + 1];
    const float r2 = pr2 + cst[OFF_R0 + 2];
    const float r3 = pr3 + cst[OFF_R0 + 3];
    const float cd = pcd + cst[OFF_C];

    float T = 0.f, S0 = 0.f, S1 = 0.f, S2 = 0.f, S3 = 0.f, den = 0.f;

    for (int base = 0; base < deg; base += 8) {
        const int ia = base + grp;
        const int ib = base + 4 + grp;
        const bool va = ia < deg;
        const bool vb = ib < deg;
        const nint4 Ea = P.csr[nbase + (va ? ia : 0)];
        const nint4 Eb = P.csr[nbase + (vb ? ib : 0)];
        const float xsa = P.x[(size_t)Ea.x * 16 + cg_];
        const float xsb = P.x[(size_t)Eb.x * 16 + cg_];
        {
            const float A0 = bf_lo((unsigned)Ea.z), A1 = bf_hi((unsigned)Ea.z);
            const float A2 = bf_lo((unsigned)Ea.w), A3 = bf_hi((unsigned)Ea.w);
            float p = y * xsa;
            p += __shfl_xor(p, 1);
            p += __shfl_xor(p, 2);
            p += __shfl_xor(p, 4);
            p += __shfl_xor(p, 8);
            p += cd + A0 * r0 + A1 * r1 + A2 * r2 + A3 * r3;
            const float a = va ? __expf(p * 0.125f) : 0.f;
            T += a * xsa;
            S0 += a * A0; S1 += a * A1; S2 += a * A2; S3 += a * A3;
            den += a;
        }
        {
            const float A0 = bf_lo((unsigned)Eb.z), A1 = bf_hi((unsigned)Eb.z);
            const float A2 = bf_lo((unsigned)Eb.w), A3 = bf_hi((unsigned)Eb.w);
            float p = y * xsb;
            p += __shfl_xor(p, 1);
            p += __shfl_xor(p, 2);
            p += __shfl_xor(p, 4);
            p += __shfl_xor(p, 8);
            p += cd + A0 * r0 + A1 * r1 + A2 * r2 + A3 * r3;
            const float a = vb ? __expf(p * 0.125f) : 0.f;
            T += a * xsb;
            S0 += a * A0; S1 += a * A1; S2 += a * A2; S3 += a * A3;
            den += a;
        }
    }

    T   += __shfl_xor(T, 16);   T   += __shfl_xor(T, 32);
    den += __shfl_xor(den, 16); den += __shfl_xor(den, 32);
    S0  += __shfl_xor(S0, 16);  S0  += __shfl_xor(S0, 32);
    S1  += __shfl_xor(S1, 16);  S1  += __shfl_xor(S1, 32);
    S2  += __shfl_xor(S2, 16);  S2  += __shfl_xor(S2, 32);
    S3  += __shfl_xor(S3, 16);  S3  += __shfl_xor(S3, 32);

    const float inv = 1.f / (den + 1e-16f);
    const float Ti = T * inv;

    float hp[8];
#pragma unroll
    for (int j = 0; j < 8; ++j)
        hp[j] = Ti * cst[OFF_PV + cg_ * 8 + j] + xd * cst[OFF_PS + cg_ * 8 + j];
#pragma unroll
    for (int j = 0; j < 8; ++j) {
        hp[j] += __shfl_xor(hp[j], 1);
        hp[j] += __shfl_xor(hp[j], 2);
        hp[j] += __shfl_xor(hp[j], 4);
        hp[j] += __shfl_xor(hp[j], 8);
    }
    const float dinv = den * inv;
    float val = P.b2[0];
#pragma unroll
    for (int j = 0; j < 8; ++j) {
        const float hid = hp[j]
            + inv * (S0 * cst[OFF_PE + 0 * 8 + j] + S1 * cst[OFF_PE + 1 * 8 + j]
                   + S2 * cst[OFF_PE + 2 * 8 + j] + S3 * cst[OFF_PE + 3 * 8 + j])
            + dinv * cst[OFF_BH1 + j] + cst[OFF_BH2 + j];
        val += fmaxf(hid, 0.f) * P.W2[j];
    }

    if (l == 0) P.g[n] = val;
}

// ---------------------------------------------------------------------------
// K3: out[e] = g[dst[e]] — coalesced read of dst + write of out; g is
// 400 KB, L2-resident.
// ---------------------------------------------------------------------------
__global__ __launch_bounds__(256) void k_out(
    const int* __restrict__ dst, const float* __restrict__ g,
    float* __restrict__ out, int E)
{
    const int e = blockIdx.x * 256 + threadIdx.x;
    if (e < E) out[e] = g[dst[e]];
}

// ---------------------------------------------------------------------------
extern "C" void kernel_launch(void* const* d_in, const int* in_sizes, int n_in,
                              void* d_out, int out_size, void* d_ws, size_t ws_size,
                              hipStream_t stream)
{
    Params P;
    P.src = (const int*)d_in[0];
    P.dst = (const int*)d_in[1];
    P.x   = (const float*)d_in[3];
    P.ea4 = (const float4*)d_in[4];
    P.Wx  = (const float*)d_in[5];
    P.bx  = (const float*)d_in[6];
    P.Wq  = (const float*)d_in[7];
    P.bq  = (const float*)d_in[8];
    P.Wk  = (const float*)d_in[9];
    P.bk  = (const float*)d_in[10];
    P.Wv  = (const float*)d_in[11];
    P.bv  = (const float*)d_in[12];
    P.We  = (const float*)d_in[13];
    P.Ws  = (const float*)d_in[14];
    P.bs  = (const float*)d_in[15];
    P.W1  = (const float*)d_in[16];
    P.b1  = (const float*)d_in[17];
    P.W2  = (const float*)d_in[18];
    P.b2  = (const float*)d_in[19];

    P.E = in_sizes[0];
    P.N = in_sizes[3] / 16;
    P.out = (float*)d_out;

    // workspace layout (~77 MB)
    P.csr    = (nint4*)d_ws;                        // N*CAP records
    P.cursor = (int*)(P.csr + (size_t)P.N * CAP);   // N ints
    P.cst    = (float*)(P.cursor + P.N);            // CST_N floats
    P.g      = P.cst + CST_N;                       // N floats

    hipMemsetAsync(P.cursor, 0, (size_t)P.N * sizeof(int), stream);

    const int nbE = (P.E + 255) / 256;
    k_fill<<<nbE + 1, 256, 0, stream>>>(P);
    k_agg<<<(P.N + 1) / 2, 128, 0, stream>>>(P);
    k_out<<<nbE, 256, 0, stream>>>(P.dst, P.g, P.out, P.E);
}

// Round 14
// 259.195 us; speedup vs baseline: 2.2556x; 1.1264x over previous
//
#include <hip/hip_runtime.h>

#define CAP 48      // padded CSR row capacity. deg ~ Poisson(12): P(>48) < 1e-9.

typedef int nint4 __attribute__((ext_vector_type(4)));

// constant-block offsets (floats) — global cst buffer
#define OFF_M   0     // M[i][j] 16x16 : i*16+j
#define OFF_U   256   // u[16]
#define OFF_W   272   // w[16]
#define OFF_C   288   // scalar
#define OFF_R   292   // R[j][i] 4x16 : j*16+i
#define OFF_R0  356   // r0[4]
#define OFF_PV  360   // Pv[cg][j] 16x8 : cg*8+j
#define OFF_PE  488   // Pe[m][j] 4x8
#define OFF_PS  520   // Ps[cg][j] 16x8
#define OFF_BH1 648   // bh1[8]  (bfv @ W1)
#define OFF_BH2 656   // bh2[8]  (bfs @ W1 + b1)
#define CST_N   664

// f32 -> bf16 (RNE), returned in low 16 bits
__device__ __forceinline__ unsigned f2bf(float f) {
    unsigned u = __float_as_uint(f);
    u += 0x7fffu + ((u >> 16) & 1u);
    return u >> 16;
}
__device__ __forceinline__ float bf_lo(unsigned u) { return __uint_as_float(u << 16); }
__device__ __forceinline__ float bf_hi(unsigned u) { return __uint_as_float(u & 0xffff0000u); }

struct Params {
    const int* src; const int* dst; const float4* ea4; const float* x;
    const float* Wx; const float* bx;
    const float* Wq; const float* bq;
    const float* Wk; const float* bk;
    const float* Wv; const float* bv;
    const float* We; const float* Ws; const float* bs;
    const float* W1; const float* b1; const float* W2; const float* b2;
    int* cursor; nint4* csr; float* cst;
    float* yv; float* rv; float* cdv; float* g; float* out;
    int N, E;
};

// ---------------------------------------------------------------------------
// fold (block 0 of k_init): collapse all weights to 16-dim operators:
//   M = Wfq Wfk^T; u = Wfk bfq; w = Wfq bfk; c = bfq.bfk
//   R = We Wfq^T; r0 = We bfq
//   Pv = Wfv W1; Ps = Wfs W1; Pe = We W1; bh1 = bfv W1; bh2 = bfs W1 + b1
// ---------------------------------------------------------------------------
__device__ void do_fold(const Params& P, float* __restrict__ cst)
{
    __shared__ float sWf[4][16][64];
    __shared__ float sbf[4][64];
    const int t = threadIdx.x;
    const int c = t & 63, m = t >> 6;
    const float* W; const float* b;
    switch (m) {
        case 0:  W = P.Wq; b = P.bq; break;
        case 1:  W = P.Wk; b = P.bk; break;
        case 2:  W = P.Wv; b = P.bv; break;
        default: W = P.Ws; b = P.bs; break;
    }
    float acc[16];
#pragma unroll
    for (int i = 0; i < 16; ++i) acc[i] = 0.f;
    float bacc = b[c];
    for (int j = 0; j < 64; ++j) {
        const float wv = W[j * 64 + c];
        bacc += P.bx[j] * wv;
#pragma unroll
        for (int i = 0; i < 16; ++i) acc[i] += P.Wx[i * 64 + j] * wv;
    }
#pragma unroll
    for (int i = 0; i < 16; ++i) sWf[m][i][c] = acc[i];
    sbf[m][c] = bacc;
    __syncthreads();

    {
        const int i = t >> 4, j = t & 15;
        float s = 0.f;
        for (int cc = 0; cc < 64; ++cc) s += sWf[0][i][cc] * sWf[1][j][cc];
        cst[OFF_M + i * 16 + j] = s;
    }
    if (t < 16) {
        float su = 0.f, sw = 0.f;
        for (int cc = 0; cc < 64; ++cc) {
            su += sWf[1][t][cc] * sbf[0][cc];
            sw += sWf[0][t][cc] * sbf[1][cc];
        }
        cst[OFF_U + t] = su;
        cst[OFF_W + t] = sw;
    }
    if (t == 0) {
        float s = 0.f;
        for (int cc = 0; cc < 64; ++cc) s += sbf[0][cc] * sbf[1][cc];
        cst[OFF_C] = s;
    }
    if (t < 64) {
        const int j = t >> 4, i = t & 15;
        float s = 0.f;
        for (int cc = 0; cc < 64; ++cc) s += P.We[j * 64 + cc] * sWf[0][i][cc];
        cst[OFF_R + j * 16 + i] = s;
    }
    if (t < 4) {
        float s = 0.f;
        for (int cc = 0; cc < 64; ++cc) s += P.We[t * 64 + cc] * sbf[0][cc];
        cst[OFF_R0 + t] = s;
    }
    if (t < 128) {
        const int i = t >> 3, j = t & 7;
        float sv = 0.f, ss = 0.f;
        for (int cc = 0; cc < 64; ++cc) {
            const float w1 = P.W1[cc * 8 + j];
            sv += sWf[2][i][cc] * w1;
            ss += sWf[3][i][cc] * w1;
        }
        cst[OFF_PV + i * 8 + j] = sv;
        cst[OFF_PS + i * 8 + j] = ss;
    }
    if (t < 32) {
        const int mm = t >> 3, j = t & 7;
        float s = 0.f;
        for (int cc = 0; cc < 64; ++cc) s += P.We[mm * 64 + cc] * P.W1[cc * 8 + j];
        cst[OFF_PE + mm * 8 + j] = s;
    }
    if (t < 8) {
        float s1 = 0.f, s2 = 0.f;
        for (int cc = 0; cc < 64; ++cc) {
            const float w1 = P.W1[cc * 8 + t];
            s1 += sbf[2][cc] * w1;
            s2 += sbf[3][cc] * w1;
        }
        cst[OFF_BH1 + t] = s1;
        cst[OFF_BH2 + t] = s2 + P.b1[t];
    }
}

// ---------------------------------------------------------------------------
// K0: block 0 = fold; blocks 1.. zero the cursor (replaces memset).
// ---------------------------------------------------------------------------
__global__ __launch_bounds__(256) void k_init(Params P)
{
    if (blockIdx.x == 0) { do_fold(P, P.cst); return; }
    const int i = (blockIdx.x - 1) * 256 + threadIdx.x;
    if (i < P.N) P.cursor[i] = 0;
}

// ---------------------------------------------------------------------------
// K1: blocks [0,nbE) bucket edges by dst (record {src, e, bf16x4(A)});
// blocks [nbE, nbE+nbN16) precompute per-node y = M x_d + u (16),
// r = R x_d + r0 (4), cd = w.x_d + c (1) — dense, coalesced.
// ---------------------------------------------------------------------------
__global__ __launch_bounds__(256) void k_fill(Params P)
{
    const int t = threadIdx.x;
    const int nbE = (P.E + 255) >> 8;
    if ((int)blockIdx.x < nbE) {
        const int e = blockIdx.x * 256 + t;
        if (e >= P.E) return;
        const int s = P.src[e];
        const int d = P.dst[e];
        const float4 A = P.ea4[e];
        const int pos = atomicAdd(&P.cursor[d], 1);
        if (pos < CAP) {
            nint4 ent;
            ent.x = s;
            ent.y = e;
            ent.z = (int)(f2bf(A.x) | (f2bf(A.y) << 16));
            ent.w = (int)(f2bf(A.z) | (f2bf(A.w) << 16));
            P.csr[(size_t)d * CAP + pos] = ent;
        }
        return;
    }

    // node precompute: 16 nodes per block
    __shared__ float sx[16][16];
    const float* __restrict__ cst = P.cst;
    const int node0 = ((int)blockIdx.x - nbE) * 16;
    const int nl = t >> 4, cg = t & 15;
    {
        const int idx = node0 * 16 + t;
        sx[nl][cg] = (idx < P.N * 16) ? P.x[idx] : 0.f;
    }
    __syncthreads();
    const int n = node0 + nl;
    if (n >= P.N) return;

    float y = cst[OFF_U + cg];
#pragma unroll
    for (int i = 0; i < 16; ++i)
        y += sx[nl][i] * cst[OFF_M + i * 16 + cg];
    P.yv[(size_t)n * 16 + cg] = y;

    if (cg < 4) {
        float r = cst[OFF_R0 + cg];
#pragma unroll
        for (int i = 0; i < 16; ++i)
            r += cst[OFF_R + cg * 16 + i] * sx[nl][i];
        P.rv[(size_t)n * 4 + cg] = r;
    } else if (cg == 4) {
        float cd = cst[OFF_C];
#pragma unroll
        for (int i = 0; i < 16; ++i)
            cd += cst[OFF_W + i] * sx[nl][i];
        P.cdv[n] = cd;
    }
}

// ---------------------------------------------------------------------------
// K2: aggregation — FOUR nodes per wave, one 16-lane group per node.
// Per group: T[cg] complete per-lane (no reduce), S/den group-replicated
// (no reduce); only per-edge p-butterfly (4 stages) and epilogue hp
// butterflies remain, each serving 4 nodes per instruction. Edge loop runs
// to wave-max degree with per-group predication, unroll x2.
// ---------------------------------------------------------------------------
__global__ __launch_bounds__(128) void k_agg(Params P)
{
    const int t = threadIdx.x;
    const int l = t & 63;
    const int wv = t >> 6;
    const int grp = l >> 4;              // group (node slot) 0..3
    const int cg  = l & 15;              // x-component index
    const int n   = (blockIdx.x * 2 + wv) * 4 + grp;
    const float* __restrict__ cst = P.cst;

    const bool vn = n < P.N;
    const int nn = vn ? n : P.N - 1;     // clamp for safe loads
    const int deg = vn ? min(P.cursor[nn], CAP) : 0;
    const size_t nbase = (size_t)nn * CAP;

    const float xd = P.x[(size_t)nn * 16 + cg];
    const float y  = P.yv[(size_t)nn * 16 + cg];
    const float4 rv = *(const float4*)&P.rv[(size_t)nn * 4];
    const float cd = P.cdv[nn];

    // wave-max degree (uniform loop bound; per-group predication inside)
    int degM = deg;
    degM = max(degM, __shfl_xor(degM, 16));
    degM = max(degM, __shfl_xor(degM, 32));

    float T = 0.f, S0 = 0.f, S1 = 0.f, S2 = 0.f, S3 = 0.f, den = 0.f;

    for (int i = 0; i < degM; i += 2) {
        const bool va = i < deg;
        const bool vb = (i + 1) < deg;
        const nint4 Ea = P.csr[nbase + (va ? i : 0)];
        const nint4 Eb = P.csr[nbase + (vb ? i + 1 : 0)];
        const int sa = va ? Ea.x : 0;    // guard poison rows (deg==0)
        const int sb = vb ? Eb.x : 0;
        const float xsa = P.x[(size_t)sa * 16 + cg];
        const float xsb = P.x[(size_t)sb * 16 + cg];
        // edge a
        {
            const float A0 = bf_lo((unsigned)Ea.z), A1 = bf_hi((unsigned)Ea.z);
            const float A2 = bf_lo((unsigned)Ea.w), A3 = bf_hi((unsigned)Ea.w);
            float p = y * xsa;
            p += __shfl_xor(p, 1);
            p += __shfl_xor(p, 2);
            p += __shfl_xor(p, 4);
            p += __shfl_xor(p, 8);
            p += cd + A0 * rv.x + A1 * rv.y + A2 * rv.z + A3 * rv.w;
            const float a = va ? __expf(p * 0.125f) : 0.f;
            T += a * xsa;
            S0 += a * A0; S1 += a * A1; S2 += a * A2; S3 += a * A3;
            den += a;
        }
        // edge b
        {
            const float A0 = bf_lo((unsigned)Eb.z), A1 = bf_hi((unsigned)Eb.z);
            const float A2 = bf_lo((unsigned)Eb.w), A3 = bf_hi((unsigned)Eb.w);
            float p = y * xsb;
            p += __shfl_xor(p, 1);
            p += __shfl_xor(p, 2);
            p += __shfl_xor(p, 4);
            p += __shfl_xor(p, 8);
            p += cd + A0 * rv.x + A1 * rv.y + A2 * rv.z + A3 * rv.w;
            const float a = vb ? __expf(p * 0.125f) : 0.f;
            T += a * xsb;
            S0 += a * A0; S1 += a * A1; S2 += a * A2; S3 += a * A3;
            den += a;
        }
    }

    // no cross-group reduction: T complete per lane; S/den replicated in group
    const float inv = 1.f / (den + 1e-16f);
    const float Ti = T * inv;

    float hp[8];
#pragma unroll
    for (int j = 0; j < 8; ++j)
        hp[j] = Ti * cst[OFF_PV + cg * 8 + j] + xd * cst[OFF_PS + cg * 8 + j];
#pragma unroll
    for (int j = 0; j < 8; ++j) {
        hp[j] += __shfl_xor(hp[j], 1);
        hp[j] += __shfl_xor(hp[j], 2);
        hp[j] += __shfl_xor(hp[j], 4);
        hp[j] += __shfl_xor(hp[j], 8);
    }
    const float dinv = den * inv;
    float val = P.b2[0];
#pragma unroll
    for (int j = 0; j < 8; ++j) {
        const float hid = hp[j]
            + inv * (S0 * cst[OFF_PE + 0 * 8 + j] + S1 * cst[OFF_PE + 1 * 8 + j]
                   + S2 * cst[OFF_PE + 2 * 8 + j] + S3 * cst[OFF_PE + 3 * 8 + j])
            + dinv * cst[OFF_BH1 + j] + cst[OFF_BH2 + j];
        val += fmaxf(hid, 0.f) * P.W2[j];
    }

    if (cg == 0 && vn) P.g[n] = val;
}

// ---------------------------------------------------------------------------
// K3: out[e] = g[dst[e]] — coalesced; g is 400 KB, L2-resident.
// ---------------------------------------------------------------------------
__global__ __launch_bounds__(256) void k_out(
    const int* __restrict__ dst, const float* __restrict__ g,
    float* __restrict__ out, int E)
{
    const int e = blockIdx.x * 256 + threadIdx.x;
    if (e < E) out[e] = g[dst[e]];
}

// ---------------------------------------------------------------------------
extern "C" void kernel_launch(void* const* d_in, const int* in_sizes, int n_in,
                              void* d_out, int out_size, void* d_ws, size_t ws_size,
                              hipStream_t stream)
{
    Params P;
    P.src = (const int*)d_in[0];
    P.dst = (const int*)d_in[1];
    P.x   = (const float*)d_in[3];
    P.ea4 = (const float4*)d_in[4];
    P.Wx  = (const float*)d_in[5];
    P.bx  = (const float*)d_in[6];
    P.Wq  = (const float*)d_in[7];
    P.bq  = (const float*)d_in[8];
    P.Wk  = (const float*)d_in[9];
    P.bk  = (const float*)d_in[10];
    P.Wv  = (const float*)d_in[11];
    P.bv  = (const float*)d_in[12];
    P.We  = (const float*)d_in[13];
    P.Ws  = (const float*)d_in[14];
    P.bs  = (const float*)d_in[15];
    P.W1  = (const float*)d_in[16];
    P.b1  = (const float*)d_in[17];
    P.W2  = (const float*)d_in[18];
    P.b2  = (const float*)d_in[19];

    P.E = in_sizes[0];
    P.N = in_sizes[3] / 16;
    P.out = (float*)d_out;

    // workspace layout (~86 MB)
    P.csr    = (nint4*)d_ws;                        // N*CAP records
    P.cursor = (int*)(P.csr + (size_t)P.N * CAP);   // N ints
    P.cst    = (float*)(P.cursor + P.N);            // CST_N floats
    P.yv     = P.cst + CST_N;                       // N*16
    P.rv     = P.yv + (size_t)P.N * 16;             // N*4
    P.cdv    = P.rv + (size_t)P.N * 4;              // N
    P.g      = P.cdv + P.N;                         // N

    const int nbE = (P.E + 255) / 256;
    const int nbN16 = (P.N + 15) / 16;

    k_init<<<1 + (P.N + 255) / 256, 256, 0, stream>>>(P);
    k_fill<<<nbE + nbN16, 256, 0, stream>>>(P);
    k_agg<<<(P.N + 7) / 8, 128, 0, stream>>>(P);
    k_out<<<nbE, 256, 0, stream>>>(P.dst, P.g, P.out, P.E);
}